// Round 1
// 404.389 us; speedup vs baseline: 1.2598x; 1.2598x over previous
//
#include <hip/hip_runtime.h>
#include <hip/hip_bf16.h>

#define NROW 50000
#define NCOL 50000
#define DDIM 128
#define CAP  32   // slots per destination row

typedef __bf16 bf16_t;
typedef __bf16 bf16x2 __attribute__((ext_vector_type(2)));
typedef __bf16 bf16x8 __attribute__((ext_vector_type(8)));
typedef float  f32x4  __attribute__((ext_vector_type(4)));

__device__ __forceinline__ float lrelu(float v) { return v >= 0.f ? v : 0.01f * v; }

// adaptive scalar load: f ? f32 : bf16
__device__ __forceinline__ float ldf(const void* p, size_t i, bool f) {
    return f ? ((const float*)p)[i] : (float)((const bf16_t*)p)[i];
}

// ---------------- dtype detector (proven in rounds 4/5 — unchanged) --------
struct TensorTab { const void* p[18]; int n[18]; };

__global__ __launch_bounds__(256) void detect_dtypes(TensorTab T, int* flags)
{
    __shared__ int vb, vf;
    const int tid = threadIdx.x;
    for (int t = 0; t < 18; ++t) {
        if (tid == 0) { vb = 0; vf = 0; }
        __syncthreads();
        const int n = T.n[t];
        const bool isFloatArr = (t != 2 && t != 3 && t != 5 && t != 6) && n >= 2;
        if (isFloatArr) {
            int nw = n / 2;
            int wi = (int)(((long long)tid * nw) >> 8);
            unsigned w = ((const unsigned*)T.p[t])[wi];
            unsigned low = w & 0xffffu;
            if (low) {
                int e = (int)((low >> 7) & 0xffu);
                if (e >= 90 && e <= 141) atomicAdd(&vb, 1);
                else                     atomicAdd(&vf, 1);
            }
        }
        __syncthreads();
        if (tid == 0) flags[t] = (isFloatArr && vf > vb) ? 1 : 0; // 1 = f32
        __syncthreads();
    }
}

// ---------------- weight prep: rearrange 4 DxD matrices into MFMA B-frag
// order (slot sIdx -> 8 contiguous bf16). One-time, tiny.
struct WPtrs { const void* W[4]; int fi[4]; };

__global__ __launch_bounds__(256) void prep_weights(WPtrs P, const int* flags,
                                                    __bf16* outp)
{
    int slot = blockIdx.x * 256 + threadIdx.x;     // 4 * 2048
    if (slot >= 4 * 2048) return;
    int m = slot >> 11, sIdx = slot & 2047;
    bool f = flags[P.fi[m]] != 0;
    int l = sIdx & 63, combo = sIdx >> 6;
    int ct = combo >> 2, kk = combo & 3;
    int col  = ct * 16 + (l & 15);
    int krow = kk * 32 + (l >> 4) * 8;
    bf16x8 v;
#pragma unroll
    for (int j = 0; j < 8; ++j)
        v[j] = (__bf16)ldf(P.W[m], (size_t)(krow + j) * DDIM + col, f);
    ((bf16x8*)outp)[slot] = v;
}

// ---------------- bucket fill: one thread per edge --------------------------
// Overflow (pos >= CAP): if ovList != nullptr, append edge to overflow list
// (applied later by scatter_overflow). Otherwise legacy direct atomic
// accumulation into pre-zeroed agg.
__global__ __launch_bounds__(256) void fill_slots(
    const int* __restrict__ dst, int nE, int* __restrict__ counts,
    int* __restrict__ slots, int* __restrict__ ovCount, int* __restrict__ ovList,
    const void* __restrict__ feat, const int* __restrict__ srcArr,
    const void* __restrict__ wArr, float* __restrict__ agg,
    const int* __restrict__ flags, int fiFeat, int fiW)
{
    int e = blockIdx.x * 256 + threadIdx.x;
    if (e >= nE) return;
    int d = dst[e];
    int pos = atomicAdd(&counts[d], 1);
    if (pos < CAP) {
        slots[(size_t)d * CAP + pos] = e;
    } else if (ovList) {
        int k = atomicAdd(ovCount, 1);   // capacity == nE, cannot overflow
        ovList[k] = e;
    } else {  // legacy fallback: exact direct atomic accumulation
        const bool fF = (fiFeat == -1) ? true : (flags[fiFeat] != 0);
        const bool fW = (fiW   == -1) ? true : (flags[fiW]   != 0);
        int s = srcArr[e];
        float wf = ldf(wArr, e, fW);
        for (int c = 0; c < DDIM; ++c)
            unsafeAtomicAdd(&agg[(size_t)d * DDIM + c],
                            ldf(feat, (size_t)s * DDIM + c, fF) * wf);
    }
}

// ---------------- overflow apply: grid-stride over ovList -------------------
__global__ __launch_bounds__(256) void scatter_overflow(
    const void* __restrict__ feat, const int* __restrict__ srcArr,
    const int* __restrict__ dstArr, const void* __restrict__ wArr,
    const int* __restrict__ ovList, const int* __restrict__ ovCount,
    float* __restrict__ agg, const int* __restrict__ flags, int fiFeat, int fiW)
{
    const bool fF = (fiFeat == -1) ? true : (flags[fiFeat] != 0);
    const bool fW = (fiW   == -1) ? true : (flags[fiW]   != 0);
    const int nOv = *ovCount;
    const int stride = gridDim.x * 256;
    for (int g = blockIdx.x * 256 + threadIdx.x; (g >> 5) < nOv; g += stride) {
        int idx = g >> 5;                 // 32 threads per edge
        int e = ovList[idx];
        int c = (g & 31) << 2;            // 4 floats per thread
        int s = srcArr[e], d = dstArr[e];
        float wf = ldf(wArr, e, fW);
        size_t base = (size_t)s * DDIM + c;
        float* ap = agg + (size_t)d * DDIM + c;
        unsafeAtomicAdd(ap + 0, ldf(feat, base + 0, fF) * wf);
        unsafeAtomicAdd(ap + 1, ldf(feat, base + 1, fF) * wf);
        unsafeAtomicAdd(ap + 2, ldf(feat, base + 2, fF) * wf);
        unsafeAtomicAdd(ap + 3, ldf(feat, base + 3, fF) * wf);
    }
}

// ---------------- segment sum: one wave per destination row ----------------
// Restructured for memory-level parallelism:
//  * lanes 0..31 prefetch ALL slot indices / src rows / weights of this row
//    in three lane-parallel loads (kills the per-edge sl->src->w chain)
//  * per-edge src/w broadcast via __shfl with uniform lane index (v_readlane)
//  * feature gather hand-unrolled x4 with two accumulators -> 4 independent
//    512B gathers in flight per wave
// ZINIT=true: agg is NOT pre-zeroed; store result directly (writes every row,
// so it doubles as the zero-fill). ZINIT=false: legacy RMW (agg pre-zeroed,
// overflow pre-accumulated).
template <bool ZINIT>
__global__ __launch_bounds__(256) void segsum(
    const void* __restrict__ feat, const int* __restrict__ srcArr,
    const void* __restrict__ wArr, const int* __restrict__ counts,
    const int* __restrict__ slots, float* __restrict__ agg, int nRows,
    const int* __restrict__ flags, int fiFeat, int fiW)
{
    const bool fF = (fiFeat == -1) ? true : (flags[fiFeat] != 0);
    const bool fW = (fiW   == -1) ? true : (flags[fiW]   != 0);
    int row = blockIdx.x * 4 + (threadIdx.x >> 6);
    if (row >= nRows) return;
    int lane = threadIdx.x & 63;

    int cnt = counts[row]; if (cnt > CAP) cnt = CAP;

    // lane-parallel index/weight prefetch (lanes 0..cnt-1; cnt <= 32)
    int sr = 0; float wv = 0.f;
    if (lane < cnt) {
        int e = slots[(size_t)row * CAP + lane];
        sr = srcArr[e];
        wv = ldf(wArr, e, fW);
    }

    float2* ap = (float2*)(agg + (size_t)row * DDIM) + lane;
    float2 acc0 = {0.f, 0.f}, acc1 = {0.f, 0.f};
    if (!ZINIT) acc0 = *ap;   // overflow contributions already accumulated

    if (fF) {
        const float2* fb = (const float2*)feat;
        int i = 0;
        for (; i + 4 <= cnt; i += 4) {
            int   a0 = __shfl(sr, i),     a1 = __shfl(sr, i + 1);
            int   a2 = __shfl(sr, i + 2), a3 = __shfl(sr, i + 3);
            float w0 = __shfl(wv, i),     w1 = __shfl(wv, i + 1);
            float w2 = __shfl(wv, i + 2), w3 = __shfl(wv, i + 3);
            float2 v0 = fb[(size_t)a0 * 64 + lane];
            float2 v1 = fb[(size_t)a1 * 64 + lane];
            float2 v2 = fb[(size_t)a2 * 64 + lane];
            float2 v3 = fb[(size_t)a3 * 64 + lane];
            acc0.x += v0.x * w0; acc0.y += v0.y * w0;
            acc1.x += v1.x * w1; acc1.y += v1.y * w1;
            acc0.x += v2.x * w2; acc0.y += v2.y * w2;
            acc1.x += v3.x * w3; acc1.y += v3.y * w3;
        }
        for (; i < cnt; ++i) {
            int   a0 = __shfl(sr, i);
            float w0 = __shfl(wv, i);
            float2 v0 = fb[(size_t)a0 * 64 + lane];
            acc0.x += v0.x * w0; acc0.y += v0.y * w0;
        }
    } else {
        const bf16x2* fb = (const bf16x2*)feat;
        int i = 0;
        for (; i + 4 <= cnt; i += 4) {
            int   a0 = __shfl(sr, i),     a1 = __shfl(sr, i + 1);
            int   a2 = __shfl(sr, i + 2), a3 = __shfl(sr, i + 3);
            float w0 = __shfl(wv, i),     w1 = __shfl(wv, i + 1);
            float w2 = __shfl(wv, i + 2), w3 = __shfl(wv, i + 3);
            bf16x2 v0 = fb[(size_t)a0 * 64 + lane];
            bf16x2 v1 = fb[(size_t)a1 * 64 + lane];
            bf16x2 v2 = fb[(size_t)a2 * 64 + lane];
            bf16x2 v3 = fb[(size_t)a3 * 64 + lane];
            acc0.x += (float)v0[0] * w0; acc0.y += (float)v0[1] * w0;
            acc1.x += (float)v1[0] * w1; acc1.y += (float)v1[1] * w1;
            acc0.x += (float)v2[0] * w2; acc0.y += (float)v2[1] * w2;
            acc1.x += (float)v3[0] * w3; acc1.y += (float)v3[1] * w3;
        }
        for (; i < cnt; ++i) {
            int   a0 = __shfl(sr, i);
            float w0 = __shfl(wv, i);
            bf16x2 v0 = fb[(size_t)a0 * 64 + lane];
            acc0.x += (float)v0[0] * w0; acc0.y += (float)v0[1] * w0;
        }
    }
    acc0.x += acc1.x; acc0.y += acc1.y;
    *ap = acc0;
}

// ---------------- legacy atomic scatter (ws-too-small fallback) -------------
__global__ __launch_bounds__(256) void scatter_any(
    const void* __restrict__ feat, const int* __restrict__ src,
    const int* __restrict__ dst, const void* __restrict__ w,
    float* __restrict__ agg, int nE,
    const int* __restrict__ flags, int fiFeat, int fiW)
{
    const bool fF = (fiFeat == -1) ? true : (flags[fiFeat] != 0);
    const bool fW = (fiW   == -1) ? true : (flags[fiW]   != 0);
    int g = blockIdx.x * 256 + threadIdx.x;
    int e = g >> 5;
    if (e >= nE) return;
    int c = (g & 31) << 2;
    int s = src[e], d = dst[e];
    float wf = ldf(w, e, fW);
    size_t base = (size_t)s * DDIM + c;
    float* ap = agg + (size_t)d * DDIM + c;
    unsafeAtomicAdd(ap + 0, ldf(feat, base + 0, fF) * wf);
    unsafeAtomicAdd(ap + 1, ldf(feat, base + 1, fF) * wf);
    unsafeAtomicAdd(ap + 2, ldf(feat, base + 2, fF) * wf);
    unsafeAtomicAdd(ap + 3, ldf(feat, base + 3, fF) * wf);
}

// ---------------- residual: out(f32) += feat (adaptive) --------------------
__global__ __launch_bounds__(256) void residual_add(
    float* __restrict__ out, const void* __restrict__ feat, int n4,
    const int* __restrict__ flags, int fiFeat)
{
    const bool fF = flags[fiFeat] != 0;
    int i = blockIdx.x * 256 + threadIdx.x;
    if (i >= n4) return;
    f32x4 o = ((const f32x4*)out)[i];
    f32x4 r;
#pragma unroll
    for (int j = 0; j < 4; ++j) r[j] = o[j] + ldf(feat, (size_t)i * 4 + j, fF);
    ((f32x4*)out)[i] = r;
}

// ---------------- fused MLP ------------------------------------------------
__device__ __forceinline__ void fill_wfrag(const void* __restrict__ W, bool f,
                                           __bf16* wf, int tid)
{
#pragma unroll
    for (int i = 0; i < 8; ++i) {
        int sIdx  = tid + i * 256;
        int l     = sIdx & 63;
        int combo = sIdx >> 6;
        int ct = combo >> 2, kk = combo & 3;
        int col  = ct * 16 + (l & 15);
        int krow = kk * 32 + (l >> 4) * 8;
        __bf16* dp = wf + (size_t)sIdx * 8;
#pragma unroll
        for (int j = 0; j < 8; ++j)
            dp[j] = (__bf16)ldf(W, (size_t)(krow + j) * DDIM + col, f);
    }
}

__device__ __forceinline__ void copy_wfrag(const __bf16* __restrict__ prep,
                                           __bf16* wf, int tid)
{
    const f32x4* sp = (const f32x4*)prep;
    f32x4* dp = (f32x4*)wf;
#pragma unroll
    for (int i = 0; i < 8; ++i) dp[tid + i * 256] = sp[tid + i * 256];
}

template <bool RESIDUAL, bool PREP>
__global__ __launch_bounds__(256) void mlp_kernel(
    const void* __restrict__ feat, const float* __restrict__ agg,
    const void* __restrict__ W1, const void* __restrict__ b1,
    const void* __restrict__ W2, const void* __restrict__ b2,
    const void* __restrict__ epsp, float* __restrict__ out, int N,
    const int* __restrict__ flags,
    int fiFeat, int fiW1, int fiB1, int fiW2, int fiB2, int fiEps,
    const __bf16* __restrict__ pW1, const __bf16* __restrict__ pW2)
{
    __shared__ alignas(16) __bf16 wf[32 * 64 * 8];  // 32 KB weight B-frags
    __shared__ alignas(16) __bf16 h1t[64 * 136];    // 17 KB h1 tile (+8 pad)

    const bool fF  = flags[fiFeat] != 0;
    const bool fB1 = flags[fiB1] != 0;
    const bool fB2 = flags[fiB2] != 0;
    const bool fE  = flags[fiEps] != 0;

    const int tid  = threadIdx.x;
    const int lane = tid & 63;
    const int wave = tid >> 6;
    const int quad = lane >> 4;
    const int r    = lane & 15;

    if (PREP) copy_wfrag(pW1, wf, tid);
    else      fill_wfrag(W1, flags[fiW1] != 0, wf, tid);

    const float eps1 = 1.f + ldf(epsp, 0, fE);
    const int rowBase = blockIdx.x * 64 + wave * 16;

    // A-fragments for layer 1: x[rowBase+r][k], k = kk*32 + quad*8 + j
    bf16x8 a[4];
    {
        int rowA = rowBase + r;
        if (rowA < N) {
            size_t fb = (size_t)rowA * DDIM + quad * 8;
            const f32x4* gp = (const f32x4*)(agg + fb);
            if (fF) {
                const f32x4* fp = (const f32x4*)((const float*)feat + fb);
#pragma unroll
                for (int kk = 0; kk < 4; ++kk) {
                    f32x4 f0 = fp[kk * 8], f1 = fp[kk * 8 + 1];
                    f32x4 g0 = gp[kk * 8], g1 = gp[kk * 8 + 1];
                    bf16x8 av;
#pragma unroll
                    for (int j = 0; j < 4; ++j) {
                        av[j]     = (__bf16)(f0[j] * eps1 + g0[j]);
                        av[j + 4] = (__bf16)(f1[j] * eps1 + g1[j]);
                    }
                    a[kk] = av;
                }
            } else {
                const bf16x8* fp = (const bf16x8*)((const bf16_t*)feat + fb);
#pragma unroll
                for (int kk = 0; kk < 4; ++kk) {
                    bf16x8 fv = fp[kk * 4];
                    f32x4 g0 = gp[kk * 8], g1 = gp[kk * 8 + 1];
                    bf16x8 av;
#pragma unroll
                    for (int j = 0; j < 4; ++j) {
                        av[j]     = (__bf16)((float)fv[j]     * eps1 + g0[j]);
                        av[j + 4] = (__bf16)((float)fv[j + 4] * eps1 + g1[j]);
                    }
                    a[kk] = av;
                }
            }
        } else {
#pragma unroll
            for (int kk = 0; kk < 4; ++kk)
#pragma unroll
                for (int j = 0; j < 8; ++j) a[kk][j] = (__bf16)0.f;
        }
    }

    __syncthreads();  // weights ready; all agg reads above are complete

    const bf16x8* wv = (const bf16x8*)wf;
#pragma unroll
    for (int ct = 0; ct < 8; ++ct) {
        f32x4 acc = {0.f, 0.f, 0.f, 0.f};
#pragma unroll
        for (int kk = 0; kk < 4; ++kk)
            acc = __builtin_amdgcn_mfma_f32_16x16x32_bf16(
                a[kk], wv[(ct * 4 + kk) * 64 + lane], acc, 0, 0, 0);
        float bias = ldf(b1, ct * 16 + r, fB1);
#pragma unroll
        for (int gg = 0; gg < 4; ++gg)   // D: m = quad*4+gg, n = ct*16+r
            h1t[(wave * 16 + quad * 4 + gg) * 136 + ct * 16 + r] =
                (__bf16)lrelu(acc[gg] + bias);
    }
    __syncthreads();  // h1 complete; wf free to reuse

    bf16x8 a2[4];
#pragma unroll
    for (int kk = 0; kk < 4; ++kk)
        a2[kk] = *(const bf16x8*)&h1t[(wave * 16 + r) * 136 + kk * 32 + quad * 8];

    if (PREP) copy_wfrag(pW2, wf, tid);
    else      fill_wfrag(W2, flags[fiW2] != 0, wf, tid);
    __syncthreads();  // W2 frags ready

#pragma unroll
    for (int ct = 0; ct < 8; ++ct) {
        f32x4 acc = {0.f, 0.f, 0.f, 0.f};
#pragma unroll
        for (int kk = 0; kk < 4; ++kk)
            acc = __builtin_amdgcn_mfma_f32_16x16x32_bf16(
                a2[kk], wv[(ct * 4 + kk) * 64 + lane], acc, 0, 0, 0);
        float bias = ldf(b2, ct * 16 + r, fB2);
#pragma unroll
        for (int gg = 0; gg < 4; ++gg) {
            int row = rowBase + quad * 4 + gg;
            if (row < N) {
                int col = ct * 16 + r;
                float v = lrelu(acc[gg] + bias);
                if (RESIDUAL) v += ldf(feat, (size_t)row * DDIM + col, fF);
                out[(size_t)row * DDIM + col] = v;
            }
        }
    }
}

extern "C" void kernel_launch(void* const* d_in, const int* in_sizes, int n_in,
                              void* d_out, int out_size, void* d_ws, size_t ws_size,
                              hipStream_t stream)
{
    const int* src_c2r = (const int*)d_in[2];
    const int* dst_c2r = (const int*)d_in[3];
    const int* src_r2c = (const int*)d_in[5];
    const int* dst_r2c = (const int*)d_in[6];
    const int nE = in_sizes[2];

    // ws layout
    int*    flags  = (int*)d_ws;                                   // 32 ints
    __bf16* wfprep = (__bf16*)((char*)d_ws + 128);                 // 128 KB
    int*    counts = (int*)((char*)d_ws + 128 + 131072);           // NROW ints
    int*    ovCnt  = counts + NROW;                                // 1 int (+pad)
    int*    slots  = counts + NROW + 8;                            // NROW*CAP ints
    int*    ovList = slots + (size_t)NROW * CAP;                   // nE ints
    const size_t NEED_BASE = 128 + 131072 + ((size_t)NROW + 8) * 4
                           + (size_t)NROW * CAP * 4;
    const size_t NEED_OV = NEED_BASE + (size_t)nE * 4;
    const bool big    = ws_size >= NEED_BASE;
    const bool haveOv = ws_size >= NEED_OV;

    TensorTab T;
    for (int i = 0; i < 18; ++i) { T.p[i] = d_in[i]; T.n[i] = in_sizes[i]; }

    // OUTPUT IS F32. out_col half doubles as the f32 agg buffer.
    float* out_row = (float*)d_out;
    float* out_col = out_row + (size_t)NROW * DDIM;
    const size_t aggBytes = (size_t)NROW * DDIM * sizeof(float);   // 25.6 MB

    const int eblocks  = (nE + 255) / 256;
    const int sblocks  = (nE * 32 + 255) / 256;
    const int mblocksR = (NROW + 63) / 64;
    const int mblocksC = (NCOL + 63) / 64;
    const int gblocksR = (NROW + 3) / 4;
    const int gblocksC = (NCOL + 3) / 4;

    detect_dtypes<<<1, 256, 0, stream>>>(T, flags);

    if (big) {
        WPtrs P;
        P.W[0] = d_in[8];  P.fi[0] = 8;    // W1_c2r
        P.W[1] = d_in[10]; P.fi[1] = 10;   // W2_c2r
        P.W[2] = d_in[12]; P.fi[2] = 12;   // W1_r2c
        P.W[3] = d_in[14]; P.fi[3] = 14;   // W2_r2c
        prep_weights<<<32, 256, 0, stream>>>(P, flags, wfprep);

        // ---- stage 1: col -> row ----
        hipMemsetAsync(counts, 0, ((size_t)NROW + 8) * 4, stream);  // + ovCnt
        if (!haveOv) hipMemsetAsync(out_col, 0, aggBytes, stream);
        fill_slots<<<eblocks, 256, 0, stream>>>(dst_c2r, nE, counts, slots,
            ovCnt, haveOv ? ovList : nullptr,
            d_in[1], src_c2r, d_in[4], out_col, flags, 1, 4);
        if (haveOv) {
            segsum<true><<<gblocksR, 256, 0, stream>>>(d_in[1], src_c2r,
                d_in[4], counts, slots, out_col, NROW, flags, 1, 4);
            scatter_overflow<<<256, 256, 0, stream>>>(d_in[1], src_c2r,
                dst_c2r, d_in[4], ovList, ovCnt, out_col, flags, 1, 4);
        } else {
            segsum<false><<<gblocksR, 256, 0, stream>>>(d_in[1], src_c2r,
                d_in[4], counts, slots, out_col, NROW, flags, 1, 4);
        }
        mlp_kernel<false, true><<<mblocksR, 256, 0, stream>>>(
            d_in[0], out_col, d_in[8], d_in[9], d_in[10], d_in[11], d_in[16],
            out_row, NROW, flags, 0, 8, 9, 10, 11, 16,
            wfprep + 0 * 16384, wfprep + 1 * 16384);

        // ---- stage 2: row -> col ----
        hipMemsetAsync(counts, 0, ((size_t)NROW + 8) * 4, stream);
        if (!haveOv) hipMemsetAsync(out_col, 0, aggBytes, stream);
        fill_slots<<<eblocks, 256, 0, stream>>>(dst_r2c, nE, counts, slots,
            ovCnt, haveOv ? ovList : nullptr,
            out_row, src_r2c, d_in[7], out_col, flags, -1, 7);
        if (haveOv) {
            segsum<true><<<gblocksC, 256, 0, stream>>>(out_row, src_r2c,
                d_in[7], counts, slots, out_col, NCOL, flags, -1, 7);
            scatter_overflow<<<256, 256, 0, stream>>>(out_row, src_r2c,
                dst_r2c, d_in[7], ovList, ovCnt, out_col, flags, -1, 7);
        } else {
            segsum<false><<<gblocksC, 256, 0, stream>>>(out_row, src_r2c,
                d_in[7], counts, slots, out_col, NCOL, flags, -1, 7);
        }
        // residual AFTER all gathers of pre-residual out_row
        residual_add<<<(NROW * DDIM / 4 + 255) / 256, 256, 0, stream>>>(
            out_row, d_in[0], NROW * DDIM / 4, flags, 0);
        mlp_kernel<true, true><<<mblocksC, 256, 0, stream>>>(
            d_in[1], out_col, d_in[12], d_in[13], d_in[14], d_in[15], d_in[17],
            out_col, NCOL, flags, 1, 12, 13, 14, 15, 17,
            wfprep + 2 * 16384, wfprep + 3 * 16384);
    } else {
        // legacy round-5 path (atomic scatter, internal weight fill)
        hipMemsetAsync(out_col, 0, aggBytes, stream);
        scatter_any<<<sblocks, 256, 0, stream>>>(d_in[1], src_c2r, dst_c2r,
            d_in[4], out_col, nE, flags, 1, 4);
        mlp_kernel<false, false><<<mblocksR, 256, 0, stream>>>(
            d_in[0], out_col, d_in[8], d_in[9], d_in[10], d_in[11], d_in[16],
            out_row, NROW, flags, 0, 8, 9, 10, 11, 16, nullptr, nullptr);

        hipMemsetAsync(out_col, 0, aggBytes, stream);
        scatter_any<<<sblocks, 256, 0, stream>>>(out_row, src_r2c, dst_r2c,
            d_in[7], out_col, nE, flags, -1, 7);
        residual_add<<<(NROW * DDIM / 4 + 255) / 256, 256, 0, stream>>>(
            out_row, d_in[0], NROW * DDIM / 4, flags, 0);
        mlp_kernel<true, false><<<mblocksC, 256, 0, stream>>>(
            d_in[1], out_col, d_in[12], d_in[13], d_in[14], d_in[15], d_in[17],
            out_col, NCOL, flags, 1, 12, 13, 14, 15, 17, nullptr, nullptr);
    }
}